// Round 11
// baseline (692.495 us; speedup 1.0000x reference)
//
#include <hip/hip_runtime.h>
#include <hip/hip_bf16.h>

#define NUM_U 100000
#define NUM_I 100000
#define NE    1600000
#define NL    100000
#define CAP   48
#define NBIN  391        // ceil(100000/256) coarse bins (dst>>8)
#define BINCAP 4608      // per-bin capacity; E[bin]=4096, +8 sigma
#define ROUND  4096      // edges per partition block
#define PB    391        // partition blocks per edge type = ceil(NE/ROUND)

typedef __attribute__((ext_vector_type(4))) float floatx4;
typedef __attribute__((ext_vector_type(8))) short shortx8;
typedef __attribute__((ext_vector_type(4))) unsigned uintx4;
typedef unsigned long long u64;

__device__ __forceinline__ float bf_lo(unsigned v) { return __uint_as_float(v << 16); }
__device__ __forceinline__ float bf_hi(unsigned v) { return __uint_as_float(v & 0xffff0000u); }

__device__ __forceinline__ unsigned pack_bf16x2(float lo, float hi) {
    __hip_bfloat16 l = __float2bfloat16(lo);
    __hip_bfloat16 h = __float2bfloat16(hi);
    unsigned short ul = *(unsigned short*)&l;
    unsigned short uh = *(unsigned short*)&h;
    return (unsigned)ul | ((unsigned)uh << 16);
}

__device__ __forceinline__ int clampi(int x, int hi) {
    return min(max(x, 0), hi - 1);
}

// -------- prep1: transpose 4 weight pairs -> bf16 Bt, zero bin_cursor,
// zero f32 tail of d_out beyond NL.
__global__ void prep1_kernel(
    const float* __restrict__ w1l_rates, const float* __restrict__ w1r_rates,
    const float* __restrict__ w1l_rev,   const float* __restrict__ w1r_rev,
    const float* __restrict__ w2l_rates, const float* __restrict__ w2r_rates,
    const float* __restrict__ w2l_rev,   const float* __restrict__ w2r_rev,
    short* __restrict__ Bt, int* __restrict__ bin_cursor,
    float* __restrict__ tailp, int ntail) {
    int idx = blockIdx.x * blockDim.x + threadIdx.x;
    if (idx < 2 * NBIN) bin_cursor[idx] = 0;
    if (idx < 4 * 32768) {
        int which = idx >> 15;
        int r = idx & 32767;
        int n = r >> 8;
        int k = r & 255;
        const float *wl, *wr;
        switch (which) {
            case 0:  wl = w1l_rates; wr = w1r_rates; break;
            case 1:  wl = w1l_rev;   wr = w1r_rev;   break;
            case 2:  wl = w2l_rates; wr = w2r_rates; break;
            default: wl = w2l_rev;   wr = w2r_rev;   break;
        }
        float v = (k < 128) ? wl[k * 128 + n] : wr[(k - 128) * 128 + n];
        __hip_bfloat16 b = __float2bfloat16(v);
        Bt[idx] = *(const short*)&b;
    } else {
        int t = idx - 4 * 32768;
        if (t < ntail) tailp[t] = 0.0f;
    }
}

// -------- both emb tables f32 [N][128] -> packed bf16x2, one dispatch
__global__ void conv2_kernel(const float* __restrict__ emb_u, const float* __restrict__ emb_i,
                             unsigned* __restrict__ xu, unsigned* __restrict__ xi) {
    int i = blockIdx.x * blockDim.x + threadIdx.x;
    const int nu = NUM_U * 64;
    if (i < nu) {
        float2 v = ((const float2*)emb_u)[i];
        xu[i] = pack_bf16x2(v.x, v.y);
    } else if (i < nu + NUM_I * 64) {
        int j = i - nu;
        float2 v = ((const float2*)emb_i)[j];
        xi[j] = pack_bf16x2(v.x, v.y);
    }
}

// -------- phase P (both edge types): block-local counting sort by dst>>8
__global__ __launch_bounds__(256) void partition2_kernel(
    const int* __restrict__ edges0, const int* __restrict__ edges1,
    u64* __restrict__ bd0, u64* __restrict__ bd1, int* __restrict__ cur) {
    __shared__ int hist[NBIN];
    __shared__ int prefix[NBIN];
    __shared__ int gbase[NBIN];
    __shared__ __align__(16) u64 sorted[ROUND];

    const int type = (blockIdx.x >= PB) ? 1 : 0;
    const int* edges = type ? edges1 : edges0;
    u64* bin_data = type ? bd1 : bd0;
    int* bin_cursor = cur + type * NBIN;
    const int blk  = blockIdx.x - type * PB;
    const int tid  = threadIdx.x;
    const int lane = tid & 63;
    const int wv   = tid >> 6;
    const int base = blk * ROUND;

    for (int k = tid; k < NBIN; k += 256) hist[k] = 0;
    __syncthreads();

    int mybin[16], myrank[16], mysrc[16], mydst[16];
#pragma unroll
    for (int r = 0; r < 16; r++) {
        int i = base + r * 256 + tid;
        mybin[r] = -1;
        if (i < NE) {
            mysrc[r] = clampi(edges[i], NUM_U);
            mydst[r] = clampi(edges[i + NE], NUM_I);
            mybin[r] = mydst[r] >> 8;
            myrank[r] = atomicAdd(&hist[mybin[r]], 1);
        }
    }
    __syncthreads();

    if (wv == 0) {   // exclusive scan of hist -> prefix
        int carry = 0;
        for (int c = 0; c < NBIN; c += 64) {
            int idx = c + lane;
            int h = (idx < NBIN) ? hist[idx] : 0;
            int v = h;
            for (int o = 1; o < 64; o <<= 1) {
                int t = __shfl_up(v, o);
                if (lane >= o) v += t;
            }
            if (idx < NBIN) prefix[idx] = v - h + carry;
            carry += __shfl(v, 63);
        }
    }
    __syncthreads();

#pragma unroll
    for (int r = 0; r < 16; r++) {
        if (mybin[r] >= 0) {
            int j = prefix[mybin[r]] + myrank[r];
            sorted[j] = ((u64)(unsigned)mydst[r] << 32) | (unsigned)mysrc[r];
        }
    }
    __syncthreads();

    for (int b = tid; b < NBIN; b += 256) {
        int cnt = hist[b];
        gbase[b] = (cnt > 0) ? atomicAdd(&bin_cursor[b], cnt) : 0;
    }
    __syncthreads();

    int total = min(ROUND, NE - base);
    for (int j = tid; j < total; j += 256) {
        u64 e = sorted[j];
        int b = (int)(e >> 40);
        int pos = gbase[b] + (j - prefix[b]);
        if (pos < BINCAP)
            bin_data[(size_t)b * BINCAP + pos] = e;
    }
}

// -------- phase Q (both edge types): one block per bin; LDS bucket build
__global__ __launch_bounds__(256) void binscatter2_kernel(
    const u64* __restrict__ bd0, const u64* __restrict__ bd1, const int* __restrict__ cur,
    int* __restrict__ deg0, int* __restrict__ bucket0,
    int* __restrict__ deg1, int* __restrict__ bucket1) {
    __shared__ int lbucket[256 * CAP];   // 48 KB
    __shared__ int ldeg[256];
    const int type = (blockIdx.x >= NBIN) ? 1 : 0;
    const int b = blockIdx.x - type * NBIN;
    const u64* bin_data = type ? bd1 : bd0;
    int* deg = type ? deg1 : deg0;
    int* bucket = type ? bucket1 : bucket0;
    const int tid = threadIdx.x;
    const int dstbase = b << 8;
    const int n_dst = NUM_I;

    ldeg[tid] = 0;
    __syncthreads();

    int count = min(cur[type * NBIN + b], BINCAP);
    for (int j = tid; j < count; j += 256) {
        u64 e = bin_data[(size_t)b * BINCAP + j];
        int src = (int)(unsigned)e;
        int dl = ((int)(e >> 32)) & 255;
        int pos = atomicAdd(&ldeg[dl], 1);
        if (pos < CAP) lbucket[dl * CAP + pos] = src;
    }
    __syncthreads();

    if (dstbase + tid < n_dst) deg[dstbase + tid] = ldeg[tid];
    int limit = min(256, n_dst - dstbase) * CAP;
    for (int k = tid; k < limit; k += 256)
        bucket[(size_t)dstbase * CAP + k] = lbucket[k];
}

// -------- merged aggregation (both edge types). One wave per dst node;
// readlane broadcasts keep src row bases in SGPRs; deg/bucket reads stay
// nontemporal. Mean stores are REGULAR (not nontemporal): R10's gemm counters
// showed nontemporal mean stores push the mean to HBM (FETCH == table size in
// gemm), making gemm's A-reads HBM-latency-bound. Regular stores keep mean in
// L2/L3 for the immediately-following gemm.
__global__ __launch_bounds__(256) void agg2_kernel(
    const int* __restrict__ degA, const int* __restrict__ bucketA,
    const unsigned* __restrict__ xA, unsigned* __restrict__ outA,
    const int* __restrict__ degB, const int* __restrict__ bucketB,
    const unsigned* __restrict__ xB, unsigned* __restrict__ outB) {
    const int bid = blockIdx.x;
    const int g = bid & 7;
    const int typeB = (g >= 4);
    const int gidx = (bid >> 3) * 4 + (g & 3);   // 0..24999 per type
    const int node = gidx * 4 + (threadIdx.x >> 6);
    const int lane = threadIdx.x & 63;
    if (node >= NUM_I) return;   // NUM_I == NUM_U

    const int* deg; const int* bucket; const unsigned* xb; unsigned* mo;
    if (!typeB) { deg = degA; bucket = bucketA; xb = xA; mo = outA; }
    else        { deg = degB; bucket = bucketB; xb = xB; mo = outB; }

    int d = __builtin_nontemporal_load(&deg[node]);
    int cnt = min(d, CAP);
    int srcs = (lane < cnt) ? __builtin_nontemporal_load(&bucket[(size_t)node * CAP + lane]) : 0;
    float a0 = 0.f, a1 = 0.f;
    int e = 0;
    for (; e + 8 <= cnt; e += 8) {
        int s0 = __builtin_amdgcn_readlane(srcs, e + 0);
        int s1 = __builtin_amdgcn_readlane(srcs, e + 1);
        int s2 = __builtin_amdgcn_readlane(srcs, e + 2);
        int s3 = __builtin_amdgcn_readlane(srcs, e + 3);
        int s4 = __builtin_amdgcn_readlane(srcs, e + 4);
        int s5 = __builtin_amdgcn_readlane(srcs, e + 5);
        int s6 = __builtin_amdgcn_readlane(srcs, e + 6);
        int s7 = __builtin_amdgcn_readlane(srcs, e + 7);
        unsigned v0 = xb[(size_t)s0 * 64 + lane];
        unsigned v1 = xb[(size_t)s1 * 64 + lane];
        unsigned v2 = xb[(size_t)s2 * 64 + lane];
        unsigned v3 = xb[(size_t)s3 * 64 + lane];
        unsigned v4 = xb[(size_t)s4 * 64 + lane];
        unsigned v5 = xb[(size_t)s5 * 64 + lane];
        unsigned v6 = xb[(size_t)s6 * 64 + lane];
        unsigned v7 = xb[(size_t)s7 * 64 + lane];
        a0 += bf_lo(v0) + bf_lo(v1) + bf_lo(v2) + bf_lo(v3)
            + bf_lo(v4) + bf_lo(v5) + bf_lo(v6) + bf_lo(v7);
        a1 += bf_hi(v0) + bf_hi(v1) + bf_hi(v2) + bf_hi(v3)
            + bf_hi(v4) + bf_hi(v5) + bf_hi(v6) + bf_hi(v7);
    }
    for (; e + 4 <= cnt; e += 4) {
        int s0 = __builtin_amdgcn_readlane(srcs, e + 0);
        int s1 = __builtin_amdgcn_readlane(srcs, e + 1);
        int s2 = __builtin_amdgcn_readlane(srcs, e + 2);
        int s3 = __builtin_amdgcn_readlane(srcs, e + 3);
        unsigned v0 = xb[(size_t)s0 * 64 + lane];
        unsigned v1 = xb[(size_t)s1 * 64 + lane];
        unsigned v2 = xb[(size_t)s2 * 64 + lane];
        unsigned v3 = xb[(size_t)s3 * 64 + lane];
        a0 += bf_lo(v0) + bf_lo(v1) + bf_lo(v2) + bf_lo(v3);
        a1 += bf_hi(v0) + bf_hi(v1) + bf_hi(v2) + bf_hi(v3);
    }
    for (; e < cnt; e++) {
        int s0 = __builtin_amdgcn_readlane(srcs, e);
        unsigned v0 = xb[(size_t)s0 * 64 + lane];
        a0 += bf_lo(v0); a1 += bf_hi(v0);
    }
    float scale = 1.0f / (float)max(d, 1);
    mo[(size_t)node * 64 + lane] = pack_bf16x2(a0 * scale, a1 * scale);
}

// -------- gemmw v2: zero-LDS, zero-barrier fused GEMM with ALL 8 A-fragments
// explicitly preloaded into registers before any MFMA (one latency window
// instead of 8 serial ones; VGPR ~95, still >=5 waves/SIMD). Block = 64 rows;
// wave = 16 rows x full 128 cols (acc[8]); rowsum via 16-lane shfl_xor.
// In-place on x is safe: each wave reads only its own 16 rows before writing.
// out = relu(normalize(mean@wl + b + x@wr)).
__global__ __launch_bounds__(256) void gemmw_kernel(
    const unsigned* __restrict__ meanA, unsigned* __restrict__ xA,
    const short* __restrict__ BtA, const float* __restrict__ biasA,
    const unsigned* __restrict__ meanB, unsigned* __restrict__ xB,
    const short* __restrict__ BtB, const float* __restrict__ biasB,
    int nblocksA) {
    const int half = (blockIdx.x >= nblocksA) ? 1 : 0;
    const unsigned* meanb = half ? meanB : meanA;
    unsigned* xb = half ? xB : xA;
    const short* Bt = half ? BtB : BtA;
    const float* bias = half ? biasB : biasA;
    const int rb = (blockIdx.x - half * nblocksA) * 64;

    const int lane = threadIdx.x & 63;
    const int wv   = threadIdx.x >> 6;
    const int l15  = lane & 15;
    const int lq   = lane >> 4;

    const int grow = rb + wv * 16 + l15;

    // issue all 8 A-fragment loads up front (4 from mean, 4 from x)
    uintx4 av[8];
#pragma unroll
    for (int kt = 0; kt < 8; kt++) {
        const unsigned* srcbuf = (kt < 4) ? meanb : xb;
        uintx4 v = (uintx4){0u, 0u, 0u, 0u};
        if (grow < NUM_I)
            v = *(const uintx4*)(srcbuf + (size_t)grow * 64 + (kt & 3) * 16 + lq * 4);
        av[kt] = v;
    }

    floatx4 acc[8];
#pragma unroll
    for (int nt = 0; nt < 8; nt++) {
        float b = bias[nt * 16 + l15];
        acc[nt] = (floatx4){b, b, b, b};
    }

#pragma unroll
    for (int kt = 0; kt < 8; kt++) {
        shortx8 af = *(const shortx8*)&av[kt];
#pragma unroll
        for (int nt = 0; nt < 8; nt++) {
            shortx8 bfr = *(const shortx8*)(Bt + (nt * 16 + l15) * 256 + kt * 32 + lq * 8);
            acc[nt] = __builtin_amdgcn_mfma_f32_16x16x32_bf16(af, bfr, acc[nt], 0, 0, 0);
        }
    }

#pragma unroll
    for (int r = 0; r < 4; r++) {
        float p = 0.f;
#pragma unroll
        for (int nt = 0; nt < 8; nt++) { float x = acc[nt][r]; p += x * x; }
        p += __shfl_xor(p, 1); p += __shfl_xor(p, 2);
        p += __shfl_xor(p, 4); p += __shfl_xor(p, 8);
        float inv = 1.f / fmaxf(sqrtf(p), 1e-12f);
        int grow_out = rb + wv * 16 + lq * 4 + r;
#pragma unroll
        for (int nt = 0; nt < 8; nt++) {
            float v = fmaxf(acc[nt][r] * inv, 0.f);
            float vnb = __shfl_xor(v, 1);
            if (grow_out < NUM_I && (l15 & 1) == 0)
                xb[(size_t)grow_out * 64 + ((nt * 16 + l15) >> 1)] = pack_bf16x2(v, vnb);
        }
    }
}

// -------- classifier: dot(xu2[src], xi2[dst]) per labeled edge, one wave per pair
__global__ __launch_bounds__(256) void classifier_kernel(
    const unsigned* __restrict__ xu, const unsigned* __restrict__ xi,
    const int* __restrict__ eli, float* __restrict__ out, int nL) {
    int wave = (blockIdx.x * blockDim.x + threadIdx.x) >> 6;
    int lane = threadIdx.x & 63;
    if (wave >= nL) return;
    int su = clampi(eli[wave], NUM_U);
    int di = clampi(eli[wave + nL], NUM_I);
    unsigned a = xu[(size_t)su * 64 + lane];
    unsigned b = xi[(size_t)di * 64 + lane];
    float p = bf_lo(a) * bf_lo(b) + bf_hi(a) * bf_hi(b);
    for (int o = 32; o; o >>= 1) p += __shfl_xor(p, o);
    if (lane == 0) __builtin_nontemporal_store(p, &out[wave]);
}

extern "C" void kernel_launch(void* const* d_in, const int* in_sizes, int n_in,
                              void* d_out, int out_size, void* d_ws, size_t ws_size,
                              hipStream_t stream) {
    const float* emb_user = (const float*)d_in[0];
    const float* emb_item = (const float*)d_in[1];
    const int* edge_rates = (const int*)d_in[2];
    const int* edge_rev   = (const int*)d_in[3];
    const int* eli        = (const int*)d_in[4];
    const float* b1_rates = (const float*)d_in[13];
    const float* b1_rev   = (const float*)d_in[14];
    const float* b2_rates = (const float*)d_in[15];
    const float* b2_rev   = (const float*)d_in[16];

    // workspace layout — ~142 MiB (bin_data regions alias meanI/meanU, dead before aggs)
    char* p = (char*)d_ws;
    auto alloc = [&](size_t bytes) -> void* {
        void* q = (void*)p;
        p += (bytes + 511) & ~(size_t)511;
        return q;
    };
    int* deg_rates    = (int*)alloc((size_t)NUM_I * 4);
    int* bucket_rates = (int*)alloc((size_t)NUM_I * CAP * 4);
    int* deg_rev      = (int*)alloc((size_t)NUM_U * 4);
    int* bucket_rev   = (int*)alloc((size_t)NUM_U * CAP * 4);
    unsigned* meanI = (unsigned*)alloc((size_t)NUM_I * 64 * 4);
    unsigned* meanU = (unsigned*)alloc((size_t)NUM_U * 64 * 4);
    unsigned* xi    = (unsigned*)alloc((size_t)NUM_I * 64 * 4);   // embI->xi1->xi2
    unsigned* xu    = (unsigned*)alloc((size_t)NUM_U * 64 * 4);   // embU->xu1->xu2
    short* Bt = (short*)alloc((size_t)4 * 32768 * 2);
    int* bin_cursor = (int*)alloc((size_t)2 * NBIN * 4);
    u64* bd0 = (u64*)meanI;   // 391*4608*8 = 14.4 MB <= 25.6 MB
    u64* bd1 = (u64*)meanU;

    const int gemmBlocks = (NUM_I + 63) / 64;                   // 1563
    const int agg2Blocks = 2 * ((NUM_I + 3) / 4);               // 50000
    const int conv2Blocks = ((NUM_U + NUM_I) * 64 + 255) / 256;
    const int ntail = (out_size > NL) ? (out_size - NL) : 0;
    const int prep1Blocks = 512 + (ntail + 255) / 256;

    // ---- one-time prep
    prep1_kernel<<<prep1Blocks, 256, 0, stream>>>(
        (const float*)d_in[5], (const float*)d_in[6],
        (const float*)d_in[7], (const float*)d_in[8],
        (const float*)d_in[9], (const float*)d_in[10],
        (const float*)d_in[11], (const float*)d_in[12], Bt, bin_cursor,
        (float*)d_out + NL, ntail);
    conv2_kernel<<<conv2Blocks, 256, 0, stream>>>(emb_user, emb_item, xu, xi);
    partition2_kernel<<<2 * PB, 256, 0, stream>>>(edge_rates, edge_rev, bd0, bd1, bin_cursor);
    binscatter2_kernel<<<2 * NBIN, 256, 0, stream>>>(bd0, bd1, bin_cursor,
                                                     deg_rates, bucket_rates,
                                                     deg_rev, bucket_rev);

    // ---- layer 1 (aggs read pristine bf16 embs; in-place GEMMs)
    agg2_kernel<<<agg2Blocks, 256, 0, stream>>>(deg_rates, bucket_rates, xu, meanI,
                                                deg_rev, bucket_rev, xi, meanU);
    gemmw_kernel<<<2 * gemmBlocks, 256, 0, stream>>>(meanI, xi, Bt + 0 * 32768, b1_rates,
                                                     meanU, xu, Bt + 1 * 32768, b1_rev,
                                                     gemmBlocks);

    // ---- layer 2 (identical pointers: in-place buffers)
    agg2_kernel<<<agg2Blocks, 256, 0, stream>>>(deg_rates, bucket_rates, xu, meanI,
                                                deg_rev, bucket_rev, xi, meanU);
    gemmw_kernel<<<2 * gemmBlocks, 256, 0, stream>>>(meanI, xi, Bt + 2 * 32768, b2_rates,
                                                     meanU, xu, Bt + 3 * 32768, b2_rev,
                                                     gemmBlocks);

    classifier_kernel<<<(NL * 64 + 255) / 256, 256, 0, stream>>>(xu, xi, eli,
                                                                 (float*)d_out, NL);
}

// Round 12
// 576.518 us; speedup vs baseline: 1.2012x; 1.2012x over previous
//
#include <hip/hip_runtime.h>
#include <hip/hip_bf16.h>

#define NUM_U 100000
#define NUM_I 100000
#define NE    1600000
#define NL    100000
#define CAP   48
#define NBIN  391        // ceil(100000/256) coarse bins (dst>>8)
#define BINCAP 4608      // per-bin capacity; E[bin]=4096, +8 sigma
#define ROUND  4096      // edges per partition block
#define PB    391        // partition blocks per edge type = ceil(NE/ROUND)

typedef __attribute__((ext_vector_type(4))) float floatx4;
typedef __attribute__((ext_vector_type(8))) short shortx8;
typedef __attribute__((ext_vector_type(4))) unsigned uintx4;
typedef unsigned long long u64;

__device__ __forceinline__ float bf_lo(unsigned v) { return __uint_as_float(v << 16); }
__device__ __forceinline__ float bf_hi(unsigned v) { return __uint_as_float(v & 0xffff0000u); }

__device__ __forceinline__ unsigned pack_bf16x2(float lo, float hi) {
    __hip_bfloat16 l = __float2bfloat16(lo);
    __hip_bfloat16 h = __float2bfloat16(hi);
    unsigned short ul = *(unsigned short*)&l;
    unsigned short uh = *(unsigned short*)&h;
    return (unsigned)ul | ((unsigned)uh << 16);
}

__device__ __forceinline__ int clampi(int x, int hi) {
    return min(max(x, 0), hi - 1);
}

// -------- prep1: build Bt in MFMA-FRAGMENT order, zero bin_cursor, zero d_out
// tail. Bt2 layout per type: element idx2 = (nt*8+kt)*512 + lane*8 + e holds
// B[col][k] with col = nt*16 + (lane&15), k = kt*32 + (lane>>4)*8 + e.
// A gemm B-fragment load is then 64 lanes x 16 B CONTIGUOUS (1 KB coalesced)
// instead of 16 scattered 512B-strided lines (R11's diagnosed serializer).
__global__ void prep1_kernel(
    const float* __restrict__ w1l_rates, const float* __restrict__ w1r_rates,
    const float* __restrict__ w1l_rev,   const float* __restrict__ w1r_rev,
    const float* __restrict__ w2l_rates, const float* __restrict__ w2r_rates,
    const float* __restrict__ w2l_rev,   const float* __restrict__ w2r_rev,
    short* __restrict__ Bt, int* __restrict__ bin_cursor,
    float* __restrict__ tailp, int ntail) {
    int idx = blockIdx.x * blockDim.x + threadIdx.x;
    if (idx < 2 * NBIN) bin_cursor[idx] = 0;
    if (idx < 4 * 32768) {
        int which = idx >> 15;
        int idx2 = idx & 32767;
        int e    = idx2 & 7;
        int lane = (idx2 >> 3) & 63;
        int kt   = (idx2 >> 9) & 7;
        int nt   = (idx2 >> 12) & 7;
        int col  = nt * 16 + (lane & 15);
        int k    = kt * 32 + (lane >> 4) * 8 + e;
        const float *wl, *wr;
        switch (which) {
            case 0:  wl = w1l_rates; wr = w1r_rates; break;
            case 1:  wl = w1l_rev;   wr = w1r_rev;   break;
            case 2:  wl = w2l_rates; wr = w2r_rates; break;
            default: wl = w2l_rev;   wr = w2r_rev;   break;
        }
        float v = (k < 128) ? wl[k * 128 + col] : wr[(k - 128) * 128 + col];
        __hip_bfloat16 b = __float2bfloat16(v);
        Bt[idx] = *(const short*)&b;
    } else {
        int t = idx - 4 * 32768;
        if (t < ntail) tailp[t] = 0.0f;
    }
}

// -------- both emb tables f32 [N][128] -> packed bf16x2, one dispatch
__global__ void conv2_kernel(const float* __restrict__ emb_u, const float* __restrict__ emb_i,
                             unsigned* __restrict__ xu, unsigned* __restrict__ xi) {
    int i = blockIdx.x * blockDim.x + threadIdx.x;
    const int nu = NUM_U * 64;
    if (i < nu) {
        float2 v = ((const float2*)emb_u)[i];
        xu[i] = pack_bf16x2(v.x, v.y);
    } else if (i < nu + NUM_I * 64) {
        int j = i - nu;
        float2 v = ((const float2*)emb_i)[j];
        xi[j] = pack_bf16x2(v.x, v.y);
    }
}

// -------- phase P (both edge types): block-local counting sort by dst>>8
__global__ __launch_bounds__(256) void partition2_kernel(
    const int* __restrict__ edges0, const int* __restrict__ edges1,
    u64* __restrict__ bd0, u64* __restrict__ bd1, int* __restrict__ cur) {
    __shared__ int hist[NBIN];
    __shared__ int prefix[NBIN];
    __shared__ int gbase[NBIN];
    __shared__ __align__(16) u64 sorted[ROUND];

    const int type = (blockIdx.x >= PB) ? 1 : 0;
    const int* edges = type ? edges1 : edges0;
    u64* bin_data = type ? bd1 : bd0;
    int* bin_cursor = cur + type * NBIN;
    const int blk  = blockIdx.x - type * PB;
    const int tid  = threadIdx.x;
    const int lane = tid & 63;
    const int wv   = tid >> 6;
    const int base = blk * ROUND;

    for (int k = tid; k < NBIN; k += 256) hist[k] = 0;
    __syncthreads();

    int mybin[16], myrank[16], mysrc[16], mydst[16];
#pragma unroll
    for (int r = 0; r < 16; r++) {
        int i = base + r * 256 + tid;
        mybin[r] = -1;
        if (i < NE) {
            mysrc[r] = clampi(edges[i], NUM_U);
            mydst[r] = clampi(edges[i + NE], NUM_I);
            mybin[r] = mydst[r] >> 8;
            myrank[r] = atomicAdd(&hist[mybin[r]], 1);
        }
    }
    __syncthreads();

    if (wv == 0) {   // exclusive scan of hist -> prefix
        int carry = 0;
        for (int c = 0; c < NBIN; c += 64) {
            int idx = c + lane;
            int h = (idx < NBIN) ? hist[idx] : 0;
            int v = h;
            for (int o = 1; o < 64; o <<= 1) {
                int t = __shfl_up(v, o);
                if (lane >= o) v += t;
            }
            if (idx < NBIN) prefix[idx] = v - h + carry;
            carry += __shfl(v, 63);
        }
    }
    __syncthreads();

#pragma unroll
    for (int r = 0; r < 16; r++) {
        if (mybin[r] >= 0) {
            int j = prefix[mybin[r]] + myrank[r];
            sorted[j] = ((u64)(unsigned)mydst[r] << 32) | (unsigned)mysrc[r];
        }
    }
    __syncthreads();

    for (int b = tid; b < NBIN; b += 256) {
        int cnt = hist[b];
        gbase[b] = (cnt > 0) ? atomicAdd(&bin_cursor[b], cnt) : 0;
    }
    __syncthreads();

    int total = min(ROUND, NE - base);
    for (int j = tid; j < total; j += 256) {
        u64 e = sorted[j];
        int b = (int)(e >> 40);
        int pos = gbase[b] + (j - prefix[b]);
        if (pos < BINCAP)
            bin_data[(size_t)b * BINCAP + pos] = e;
    }
}

// -------- phase Q (both edge types): one block per bin; LDS bucket build
__global__ __launch_bounds__(256) void binscatter2_kernel(
    const u64* __restrict__ bd0, const u64* __restrict__ bd1, const int* __restrict__ cur,
    int* __restrict__ deg0, int* __restrict__ bucket0,
    int* __restrict__ deg1, int* __restrict__ bucket1) {
    __shared__ int lbucket[256 * CAP];   // 48 KB
    __shared__ int ldeg[256];
    const int type = (blockIdx.x >= NBIN) ? 1 : 0;
    const int b = blockIdx.x - type * NBIN;
    const u64* bin_data = type ? bd1 : bd0;
    int* deg = type ? deg1 : deg0;
    int* bucket = type ? bucket1 : bucket0;
    const int tid = threadIdx.x;
    const int dstbase = b << 8;
    const int n_dst = NUM_I;

    ldeg[tid] = 0;
    __syncthreads();

    int count = min(cur[type * NBIN + b], BINCAP);
    for (int j = tid; j < count; j += 256) {
        u64 e = bin_data[(size_t)b * BINCAP + j];
        int src = (int)(unsigned)e;
        int dl = ((int)(e >> 32)) & 255;
        int pos = atomicAdd(&ldeg[dl], 1);
        if (pos < CAP) lbucket[dl * CAP + pos] = src;
    }
    __syncthreads();

    if (dstbase + tid < n_dst) deg[dstbase + tid] = ldeg[tid];
    int limit = min(256, n_dst - dstbase) * CAP;
    for (int k = tid; k < limit; k += 256)
        bucket[(size_t)dstbase * CAP + k] = lbucket[k];
}

// -------- merged aggregation (both edge types), R4's best-measured config
// (nontemporal mean stores — R11 proved store-type doesn't affect gemm's
// cross-XCD compulsory fetch, so keep agg's fastest form). One wave per dst
// node; readlane broadcasts keep src row bases in SGPRs.
__global__ __launch_bounds__(256) void agg2_kernel(
    const int* __restrict__ degA, const int* __restrict__ bucketA,
    const unsigned* __restrict__ xA, unsigned* __restrict__ outA,
    const int* __restrict__ degB, const int* __restrict__ bucketB,
    const unsigned* __restrict__ xB, unsigned* __restrict__ outB) {
    const int bid = blockIdx.x;
    const int g = bid & 7;
    const int typeB = (g >= 4);
    const int gidx = (bid >> 3) * 4 + (g & 3);   // 0..24999 per type
    const int node = gidx * 4 + (threadIdx.x >> 6);
    const int lane = threadIdx.x & 63;
    if (node >= NUM_I) return;   // NUM_I == NUM_U

    const int* deg; const int* bucket; const unsigned* xb; unsigned* mo;
    if (!typeB) { deg = degA; bucket = bucketA; xb = xA; mo = outA; }
    else        { deg = degB; bucket = bucketB; xb = xB; mo = outB; }

    int d = __builtin_nontemporal_load(&deg[node]);
    int cnt = min(d, CAP);
    int srcs = (lane < cnt) ? __builtin_nontemporal_load(&bucket[(size_t)node * CAP + lane]) : 0;
    float a0 = 0.f, a1 = 0.f;
    int e = 0;
    for (; e + 8 <= cnt; e += 8) {
        int s0 = __builtin_amdgcn_readlane(srcs, e + 0);
        int s1 = __builtin_amdgcn_readlane(srcs, e + 1);
        int s2 = __builtin_amdgcn_readlane(srcs, e + 2);
        int s3 = __builtin_amdgcn_readlane(srcs, e + 3);
        int s4 = __builtin_amdgcn_readlane(srcs, e + 4);
        int s5 = __builtin_amdgcn_readlane(srcs, e + 5);
        int s6 = __builtin_amdgcn_readlane(srcs, e + 6);
        int s7 = __builtin_amdgcn_readlane(srcs, e + 7);
        unsigned v0 = xb[(size_t)s0 * 64 + lane];
        unsigned v1 = xb[(size_t)s1 * 64 + lane];
        unsigned v2 = xb[(size_t)s2 * 64 + lane];
        unsigned v3 = xb[(size_t)s3 * 64 + lane];
        unsigned v4 = xb[(size_t)s4 * 64 + lane];
        unsigned v5 = xb[(size_t)s5 * 64 + lane];
        unsigned v6 = xb[(size_t)s6 * 64 + lane];
        unsigned v7 = xb[(size_t)s7 * 64 + lane];
        a0 += bf_lo(v0) + bf_lo(v1) + bf_lo(v2) + bf_lo(v3)
            + bf_lo(v4) + bf_lo(v5) + bf_lo(v6) + bf_lo(v7);
        a1 += bf_hi(v0) + bf_hi(v1) + bf_hi(v2) + bf_hi(v3)
            + bf_hi(v4) + bf_hi(v5) + bf_hi(v6) + bf_hi(v7);
    }
    for (; e + 4 <= cnt; e += 4) {
        int s0 = __builtin_amdgcn_readlane(srcs, e + 0);
        int s1 = __builtin_amdgcn_readlane(srcs, e + 1);
        int s2 = __builtin_amdgcn_readlane(srcs, e + 2);
        int s3 = __builtin_amdgcn_readlane(srcs, e + 3);
        unsigned v0 = xb[(size_t)s0 * 64 + lane];
        unsigned v1 = xb[(size_t)s1 * 64 + lane];
        unsigned v2 = xb[(size_t)s2 * 64 + lane];
        unsigned v3 = xb[(size_t)s3 * 64 + lane];
        a0 += bf_lo(v0) + bf_lo(v1) + bf_lo(v2) + bf_lo(v3);
        a1 += bf_hi(v0) + bf_hi(v1) + bf_hi(v2) + bf_hi(v3);
    }
    for (; e < cnt; e++) {
        int s0 = __builtin_amdgcn_readlane(srcs, e);
        unsigned v0 = xb[(size_t)s0 * 64 + lane];
        a0 += bf_lo(v0); a1 += bf_hi(v0);
    }
    float scale = 1.0f / (float)max(d, 1);
    __builtin_nontemporal_store(pack_bf16x2(a0 * scale, a1 * scale),
                                &mo[(size_t)node * 64 + lane]);
}

// -------- gemmw v3: zero-LDS, zero-barrier; fragment-ordered Bt so every
// B-load is a fully-coalesced 1 KB read; A-fragments batch-preloaded; B
// fragments batch-loaded per kt. Block = 64 rows; wave = 16 rows x 128 cols
// (acc[8]); rowsum via 16-lane shfl_xor. In-place on x is safe (each wave
// reads only its own 16 rows before writing).
// out = relu(normalize(mean@wl + b + x@wr)).
__global__ __launch_bounds__(256) void gemmw_kernel(
    const unsigned* __restrict__ meanA, unsigned* __restrict__ xA,
    const short* __restrict__ BtA, const float* __restrict__ biasA,
    const unsigned* __restrict__ meanB, unsigned* __restrict__ xB,
    const short* __restrict__ BtB, const float* __restrict__ biasB,
    int nblocksA) {
    const int half = (blockIdx.x >= nblocksA) ? 1 : 0;
    const unsigned* meanb = half ? meanB : meanA;
    unsigned* xb = half ? xB : xA;
    const short* Bt = half ? BtB : BtA;
    const float* bias = half ? biasB : biasA;
    const int rb = (blockIdx.x - half * nblocksA) * 64;

    const int lane = threadIdx.x & 63;
    const int wv   = threadIdx.x >> 6;
    const int l15  = lane & 15;
    const int lq   = lane >> 4;

    const int grow = rb + wv * 16 + l15;

    // batch-issue all 8 A-fragment loads (4 from mean, 4 from x)
    uintx4 av[8];
#pragma unroll
    for (int kt = 0; kt < 8; kt++) {
        const unsigned* srcbuf = (kt < 4) ? meanb : xb;
        uintx4 v = (uintx4){0u, 0u, 0u, 0u};
        if (grow < NUM_I)
            v = *(const uintx4*)(srcbuf + (size_t)grow * 64 + (kt & 3) * 16 + lq * 4);
        av[kt] = v;
    }

    floatx4 acc[8];
#pragma unroll
    for (int nt = 0; nt < 8; nt++) {
        float b = bias[nt * 16 + l15];
        acc[nt] = (floatx4){b, b, b, b};
    }

#pragma unroll
    for (int kt = 0; kt < 8; kt++) {
        shortx8 af = *(const shortx8*)&av[kt];
        shortx8 bfr[8];
#pragma unroll
        for (int nt = 0; nt < 8; nt++)
            bfr[nt] = *(const shortx8*)(Bt + (nt * 8 + kt) * 512 + lane * 8);
#pragma unroll
        for (int nt = 0; nt < 8; nt++)
            acc[nt] = __builtin_amdgcn_mfma_f32_16x16x32_bf16(af, bfr[nt], acc[nt], 0, 0, 0);
    }

#pragma unroll
    for (int r = 0; r < 4; r++) {
        float p = 0.f;
#pragma unroll
        for (int nt = 0; nt < 8; nt++) { float x = acc[nt][r]; p += x * x; }
        p += __shfl_xor(p, 1); p += __shfl_xor(p, 2);
        p += __shfl_xor(p, 4); p += __shfl_xor(p, 8);
        float inv = 1.f / fmaxf(sqrtf(p), 1e-12f);
        int grow_out = rb + wv * 16 + lq * 4 + r;
#pragma unroll
        for (int nt = 0; nt < 8; nt++) {
            float v = fmaxf(acc[nt][r] * inv, 0.f);
            float vnb = __shfl_xor(v, 1);
            if (grow_out < NUM_I && (l15 & 1) == 0)
                xb[(size_t)grow_out * 64 + ((nt * 16 + l15) >> 1)] = pack_bf16x2(v, vnb);
        }
    }
}

// -------- classifier: dot(xu2[src], xi2[dst]) per labeled edge, one wave per pair
__global__ __launch_bounds__(256) void classifier_kernel(
    const unsigned* __restrict__ xu, const unsigned* __restrict__ xi,
    const int* __restrict__ eli, float* __restrict__ out, int nL) {
    int wave = (blockIdx.x * blockDim.x + threadIdx.x) >> 6;
    int lane = threadIdx.x & 63;
    if (wave >= nL) return;
    int su = clampi(eli[wave], NUM_U);
    int di = clampi(eli[wave + nL], NUM_I);
    unsigned a = xu[(size_t)su * 64 + lane];
    unsigned b = xi[(size_t)di * 64 + lane];
    float p = bf_lo(a) * bf_lo(b) + bf_hi(a) * bf_hi(b);
    for (int o = 32; o; o >>= 1) p += __shfl_xor(p, o);
    if (lane == 0) __builtin_nontemporal_store(p, &out[wave]);
}

extern "C" void kernel_launch(void* const* d_in, const int* in_sizes, int n_in,
                              void* d_out, int out_size, void* d_ws, size_t ws_size,
                              hipStream_t stream) {
    const float* emb_user = (const float*)d_in[0];
    const float* emb_item = (const float*)d_in[1];
    const int* edge_rates = (const int*)d_in[2];
    const int* edge_rev   = (const int*)d_in[3];
    const int* eli        = (const int*)d_in[4];
    const float* b1_rates = (const float*)d_in[13];
    const float* b1_rev   = (const float*)d_in[14];
    const float* b2_rates = (const float*)d_in[15];
    const float* b2_rev   = (const float*)d_in[16];

    // workspace layout — ~142 MiB (bin_data regions alias meanI/meanU, dead before aggs)
    char* p = (char*)d_ws;
    auto alloc = [&](size_t bytes) -> void* {
        void* q = (void*)p;
        p += (bytes + 511) & ~(size_t)511;
        return q;
    };
    int* deg_rates    = (int*)alloc((size_t)NUM_I * 4);
    int* bucket_rates = (int*)alloc((size_t)NUM_I * CAP * 4);
    int* deg_rev      = (int*)alloc((size_t)NUM_U * 4);
    int* bucket_rev   = (int*)alloc((size_t)NUM_U * CAP * 4);
    unsigned* meanI = (unsigned*)alloc((size_t)NUM_I * 64 * 4);
    unsigned* meanU = (unsigned*)alloc((size_t)NUM_U * 64 * 4);
    unsigned* xi    = (unsigned*)alloc((size_t)NUM_I * 64 * 4);   // embI->xi1->xi2
    unsigned* xu    = (unsigned*)alloc((size_t)NUM_U * 64 * 4);   // embU->xu1->xu2
    short* Bt = (short*)alloc((size_t)4 * 32768 * 2);
    int* bin_cursor = (int*)alloc((size_t)2 * NBIN * 4);
    u64* bd0 = (u64*)meanI;   // 391*4608*8 = 14.4 MB <= 25.6 MB
    u64* bd1 = (u64*)meanU;

    const int gemmBlocks = (NUM_I + 63) / 64;                   // 1563
    const int agg2Blocks = 2 * ((NUM_I + 3) / 4);               // 50000
    const int conv2Blocks = ((NUM_U + NUM_I) * 64 + 255) / 256;
    const int ntail = (out_size > NL) ? (out_size - NL) : 0;
    const int prep1Blocks = 512 + (ntail + 255) / 256;

    // ---- one-time prep
    prep1_kernel<<<prep1Blocks, 256, 0, stream>>>(
        (const float*)d_in[5], (const float*)d_in[6],
        (const float*)d_in[7], (const float*)d_in[8],
        (const float*)d_in[9], (const float*)d_in[10],
        (const float*)d_in[11], (const float*)d_in[12], Bt, bin_cursor,
        (float*)d_out + NL, ntail);
    conv2_kernel<<<conv2Blocks, 256, 0, stream>>>(emb_user, emb_item, xu, xi);
    partition2_kernel<<<2 * PB, 256, 0, stream>>>(edge_rates, edge_rev, bd0, bd1, bin_cursor);
    binscatter2_kernel<<<2 * NBIN, 256, 0, stream>>>(bd0, bd1, bin_cursor,
                                                     deg_rates, bucket_rates,
                                                     deg_rev, bucket_rev);

    // ---- layer 1 (aggs read pristine bf16 embs; in-place GEMMs)
    agg2_kernel<<<agg2Blocks, 256, 0, stream>>>(deg_rates, bucket_rates, xu, meanI,
                                                deg_rev, bucket_rev, xi, meanU);
    gemmw_kernel<<<2 * gemmBlocks, 256, 0, stream>>>(meanI, xi, Bt + 0 * 32768, b1_rates,
                                                     meanU, xu, Bt + 1 * 32768, b1_rev,
                                                     gemmBlocks);

    // ---- layer 2 (identical pointers: in-place buffers)
    agg2_kernel<<<agg2Blocks, 256, 0, stream>>>(deg_rates, bucket_rates, xu, meanI,
                                                deg_rev, bucket_rev, xi, meanU);
    gemmw_kernel<<<2 * gemmBlocks, 256, 0, stream>>>(meanI, xi, Bt + 2 * 32768, b2_rates,
                                                     meanU, xu, Bt + 3 * 32768, b2_rev,
                                                     gemmBlocks);

    classifier_kernel<<<(NL * 64 + 255) / 256, 256, 0, stream>>>(xu, xi, eli,
                                                                 (float*)d_out, NL);
}